// Round 5
// baseline (304.223 us; speedup 1.0000x reference)
//
#include <hip/hip_runtime.h>

#define HW    128
#define NPIX  (HW * HW)     // 16384
#define NLDS  15            // pixels per thread held in LDS
#define NREG  49            // pixels per thread held in VGPRs (64 - NLDS)

typedef float vfloat4 __attribute__((ext_vector_type(4)));

__device__ __forceinline__ float4 nt_load4(const float4* p) {
    vfloat4 t = __builtin_nontemporal_load((const vfloat4*)p);
    return make_float4(t.x, t.y, t.z, t.w);
}
__device__ __forceinline__ void nt_store4(float4* p, float4 v) {
    vfloat4 t; t.x = v.x; t.y = v.y; t.z = v.z; t.w = v.w;
    __builtin_nontemporal_store(t, (vfloat4*)p);
}

// f32 -> bf16 (RNE), packed pair. Unpack helpers must match (low = first arg).
__device__ __forceinline__ unsigned bf16_rne(float f) {
    unsigned u = __float_as_uint(f);
    return (u + 0x7FFFu + ((u >> 16) & 1u)) >> 16;
}
__device__ __forceinline__ unsigned pack2(float a, float b) {
    return bf16_rne(a) | (bf16_rne(b) << 16);
}
__device__ __forceinline__ float unlo(unsigned u) { return __uint_as_float(u << 16); }
__device__ __forceinline__ float unhi(unsigned u) { return __uint_as_float(u & 0xFFFF0000u); }

__device__ __forceinline__ void unpack8(uint4 u, float (&a)[8]) {
    a[0] = unlo(u.x); a[1] = unhi(u.x); a[2] = unlo(u.y); a[3] = unhi(u.y);
    a[4] = unlo(u.z); a[5] = unhi(u.z); a[6] = unlo(u.w); a[7] = unhi(u.w);
}

__device__ __forceinline__ void store_comb(
    float4* __restrict__ ob, int pix, int q,
    float s0, float s1, float s2, float s3,
    const float (&a)[8], const float (&b)[8], const float (&c)[8], const float (&d)[8]) {
    float4 lo, hi;
    lo.x = s0*a[0] + s1*b[0] + s2*c[0] + s3*d[0];
    lo.y = s0*a[1] + s1*b[1] + s2*c[1] + s3*d[1];
    lo.z = s0*a[2] + s1*b[2] + s2*c[2] + s3*d[2];
    lo.w = s0*a[3] + s1*b[3] + s2*c[3] + s3*d[3];
    hi.x = s0*a[4] + s1*b[4] + s2*c[4] + s3*d[4];
    hi.y = s0*a[5] + s1*b[5] + s2*c[5] + s3*d[5];
    hi.z = s0*a[6] + s1*b[6] + s2*c[6] + s3*d[6];
    hi.w = s0*a[7] + s1*b[7] + s2*c[7] + s3*d[7];
    size_t idx = (size_t)pix * 32 + q * 2;
    nt_store4(&ob[idx],     lo);
    nt_store4(&ob[idx + 1], hi);
}

// Fetch pixel i's 8-ch bf16 packet (i must be compile-time after unrolling).
#define GETPX(i) ((i) < NLDS ? perLDSv[t * NLDS + (i)] \
    : make_uint4(rg[(i) - NLDS][0], rg[(i) - NLDS][1], rg[(i) - NLDS][2], rg[(i) - NLDS][3]))

// ---------------------------------------------------------------------------
// Phase A: load own 4 blocks (nt), accumulate 8-ch sums, pack bf16 into
// regs/LDS. BK = which rotation-image block this wave owns.
//   bk0: rows h0..h0+7, cols  0..63   (p0 region, TL)
//   bk1: rows  0..63,  cols 120-h0..127-h0 (p1 region, TR)
//   bk2: rows 120-h0..127-h0, cols 64..127 (p2 region, BR)
//   bk3: rows 64..127, cols h0..h0+7  (p3 region, BL)
// ---------------------------------------------------------------------------
template <int BK>
__device__ __forceinline__ void phaseA(
    const float4* __restrict__ xb, int h0, int s, int q, int t,
    uint4* __restrict__ perLDSv, unsigned (&rg)[NREG][4],
    float4& acc0, float4& acc1) {
    #pragma unroll
    for (int i = 0; i < 64; ++i) {
        int p;
        if constexpr (BK == 0)      p = (h0 + s) * HW + i;
        else if constexpr (BK == 1) p = (s * 8 + (i >> 3)) * HW + (120 - h0) + (i & 7);
        else if constexpr (BK == 2) p = (120 - h0 + s) * HW + 64 + i;
        else                        p = (64 + s * 8 + (i >> 3)) * HW + h0 + (i & 7);
        const float4* src = xb + ((size_t)p * 32 + q * 2);
        float4 v0 = nt_load4(src);
        float4 v1 = nt_load4(src + 1);
        acc0.x += v0.x; acc0.y += v0.y; acc0.z += v0.z; acc0.w += v0.w;
        acc1.x += v1.x; acc1.y += v1.y; acc1.z += v1.z; acc1.w += v1.w;
        uint4 d = make_uint4(pack2(v0.x, v0.y), pack2(v0.z, v0.w),
                             pack2(v1.x, v1.y), pack2(v1.z, v1.w));
        if (i < NLDS) {
            perLDSv[t * NLDS + i] = d;
        } else {
            rg[i - NLDS][0] = d.x; rg[i - NLDS][1] = d.y;
            rg[i - NLDS][2] = d.z; rg[i - NLDS][3] = d.w;
        }
    }
}

// ---------------------------------------------------------------------------
// One tile = orbits (h0+DH, w in [HALF*32, HALF*32+32)), full C.
// Producers scatter orbit quadruples into the 32 KiB tile buffer; consumers
// read 4 positions, combine with cyclic weights, nt-store 4 out rows.
// DH/HALF are template constants so all rg[] indices fold at compile time.
// ---------------------------------------------------------------------------
template <int DH, int HALF>
__device__ __forceinline__ void tile_step(
    int bk, int s, int q, int t, int h0,
    const uint4* __restrict__ perLDSv, const unsigned (&rg)[NREG][4],
    uint4* __restrict__ tilev,
    float s0, float s1, float s2, float s3,
    float4* __restrict__ ob) {
    constexpr int W0 = HALF * 32;
    if (bk == 0) {
        if (s == DH) {
            #pragma unroll
            for (int i = W0; i < W0 + 32; ++i)
                tilev[(0 * 32 + (i - W0)) * 16 + q] = GETPX(i);
        }
    } else if (bk == 1) {
        if ((s >> 2) == HALF) {
            #pragma unroll
            for (int ii = 0; ii < 8; ++ii) {
                int i  = ii * 8 + (7 - DH);     // col == 127-h0-DH
                int ww = s * 8 + ii - W0;       // w = row
                tilev[(1 * 32 + ww) * 16 + q] = GETPX(i);
            }
        }
    } else if (bk == 2) {
        if (s == 7 - DH) {
            #pragma unroll
            for (int i = 32 - W0; i <= 63 - W0; ++i) {
                int ww = 63 - i - W0;           // w = 63 - i
                tilev[(2 * 32 + ww) * 16 + q] = GETPX(i);
            }
        }
    } else {
        if ((s >> 2) == 1 - HALF) {
            #pragma unroll
            for (int ii = 0; ii < 8; ++ii) {
                int i  = ii * 8 + DH;           // col == h0+DH
                int ww = 63 - s * 8 - ii - W0;  // w = 127 - row
                tilev[(3 * 32 + ww) * 16 + q] = GETPX(i);
            }
        }
    }
    __syncthreads();
    {
        int ww = t >> 4;               // 0..31
        int w  = W0 + ww;
        int h  = h0 + DH;
        uint4 u0 = tilev[(0 * 32 + ww) * 16 + q];
        uint4 u1 = tilev[(1 * 32 + ww) * 16 + q];
        uint4 u2 = tilev[(2 * 32 + ww) * 16 + q];
        uint4 u3 = tilev[(3 * 32 + ww) * 16 + q];
        float a0[8], a1[8], a2[8], a3[8];
        unpack8(u0, a0); unpack8(u1, a1); unpack8(u2, a2); unpack8(u3, a3);
        int p0 = h * HW + w;
        int p1 = w * HW + (127 - h);
        int p2 = (127 - h) * HW + (127 - w);
        int p3 = (127 - w) * HW + h;
        store_comb(ob, p0, q, s0, s1, s2, s3, a0, a1, a2, a3);
        store_comb(ob, p1, q, s0, s1, s2, s3, a1, a2, a3, a0);
        store_comb(ob, p2, q, s0, s1, s2, s3, a2, a3, a0, a1);
        store_comb(ob, p3, q, s0, s1, s2, s3, a3, a0, a1, a2);
    }
    __syncthreads();
}

// ---------------------------------------------------------------------------
// Fused kernel: grid = 256 wgs (b, h0-slice), 512 threads, 1 wg/CU
// (LDS 152 KiB). x is read from HBM exactly once; out written once.
// ---------------------------------------------------------------------------
__global__ __launch_bounds__(512, 2) void fused_rot(
    const float* __restrict__ x, const float* __restrict__ Wsel,
    const float* __restrict__ bsel, float* __restrict__ out,
    float* __restrict__ partial, unsigned* __restrict__ cnt) {
    __shared__ uint4 perLDSv[512 * NLDS];   // 120 KiB persistent bf16 pixels
    __shared__ uint4 tilev[4 * 32 * 16];    // 32 KiB exchange tile (aliases reduce buf)
    __shared__ float wts_s[4];

    const int t    = threadIdx.x;
    const int q    = t & 15;                // 8-channel slice index
    const int pg   = t >> 4;                // pixel group 0..31
    const int bk   = pg >> 3;               // block 0..3
    const int s    = pg & 7;                // sub-index in block
    const int wgid = blockIdx.x;            // 0..255
    const int b    = wgid >> 3;
    const int h0   = (wgid & 7) << 3;

    const float4* xb = (const float4*)x + (size_t)b * NPIX * 32;
    float4*       ob = (float4*)out + (size_t)b * NPIX * 32;

    unsigned rg[NREG][4];
    float4 acc0 = make_float4(0.f, 0.f, 0.f, 0.f);
    float4 acc1 = make_float4(0.f, 0.f, 0.f, 0.f);

    if (bk == 0)      phaseA<0>(xb, h0, s, q, t, perLDSv, rg, acc0, acc1);
    else if (bk == 1) phaseA<1>(xb, h0, s, q, t, perLDSv, rg, acc0, acc1);
    else if (bk == 2) phaseA<2>(xb, h0, s, q, t, perLDSv, rg, acc0, acc1);
    else              phaseA<3>(xb, h0, s, q, t, perLDSv, rg, acc0, acc1);

    // Selector partial: logit4 += acc[j] * W_sel[q*8+j][:]
    const float4* W4 = (const float4*)Wsel;
    float4 lg = make_float4(0.f, 0.f, 0.f, 0.f);
    {
        float av[8] = {acc0.x, acc0.y, acc0.z, acc0.w,
                       acc1.x, acc1.y, acc1.z, acc1.w};
        #pragma unroll
        for (int j = 0; j < 8; ++j) {
            float4 wr = W4[q * 8 + j];
            lg.x += av[j] * wr.x; lg.y += av[j] * wr.y;
            lg.z += av[j] * wr.z; lg.w += av[j] * wr.w;
        }
    }
    // Block tree-reduce (8 KiB, aliases tilev).
    float4* red = (float4*)tilev;
    red[t] = lg;
    __syncthreads();
    #pragma unroll
    for (int off = 256; off > 0; off >>= 1) {
        if (t < off) {
            float4 a = red[t], c = red[t + off];
            a.x += c.x; a.y += c.y; a.z += c.z; a.w += c.w;
            red[t] = a;
        }
        __syncthreads();
    }

    // Grid barrier (all 256 wgs co-resident by construction) + softmax.
    if (t == 0) {
        float4 r = red[0];
        __hip_atomic_store(&partial[wgid * 4 + 0], r.x, __ATOMIC_RELAXED, __HIP_MEMORY_SCOPE_AGENT);
        __hip_atomic_store(&partial[wgid * 4 + 1], r.y, __ATOMIC_RELAXED, __HIP_MEMORY_SCOPE_AGENT);
        __hip_atomic_store(&partial[wgid * 4 + 2], r.z, __ATOMIC_RELAXED, __HIP_MEMORY_SCOPE_AGENT);
        __hip_atomic_store(&partial[wgid * 4 + 3], r.w, __ATOMIC_RELAXED, __HIP_MEMORY_SCOPE_AGENT);
        __hip_atomic_fetch_add(cnt, 1u, __ATOMIC_ACQ_REL, __HIP_MEMORY_SCOPE_AGENT);
        while (__hip_atomic_load(cnt, __ATOMIC_ACQUIRE, __HIP_MEMORY_SCOPE_AGENT) < 256u)
            __builtin_amdgcn_s_sleep(2);
        float l[4] = {bsel[0], bsel[1], bsel[2], bsel[3]};
        const float inv = 1.0f / (float)NPIX;
        for (int g = 0; g < 8; ++g) {
            #pragma unroll
            for (int k = 0; k < 4; ++k)
                l[k] += __hip_atomic_load(&partial[(b * 8 + g) * 4 + k],
                                          __ATOMIC_RELAXED, __HIP_MEMORY_SCOPE_AGENT) * inv;
        }
        float m  = fmaxf(fmaxf(l[0], l[1]), fmaxf(l[2], l[3]));
        float e0 = expf(l[0] - m), e1 = expf(l[1] - m);
        float e2 = expf(l[2] - m), e3 = expf(l[3] - m);
        float is = 1.0f / (e0 + e1 + e2 + e3);
        wts_s[0] = e0 * is; wts_s[1] = e1 * is;
        wts_s[2] = e2 * is; wts_s[3] = e3 * is;
    }
    __syncthreads();
    const float s0 = wts_s[0], s1 = wts_s[1], s2 = wts_s[2], s3 = wts_s[3];

    // Phase B: 16 orbit tiles, fully static.
    tile_step<0, 0>(bk, s, q, t, h0, perLDSv, rg, tilev, s0, s1, s2, s3, ob);
    tile_step<0, 1>(bk, s, q, t, h0, perLDSv, rg, tilev, s0, s1, s2, s3, ob);
    tile_step<1, 0>(bk, s, q, t, h0, perLDSv, rg, tilev, s0, s1, s2, s3, ob);
    tile_step<1, 1>(bk, s, q, t, h0, perLDSv, rg, tilev, s0, s1, s2, s3, ob);
    tile_step<2, 0>(bk, s, q, t, h0, perLDSv, rg, tilev, s0, s1, s2, s3, ob);
    tile_step<2, 1>(bk, s, q, t, h0, perLDSv, rg, tilev, s0, s1, s2, s3, ob);
    tile_step<3, 0>(bk, s, q, t, h0, perLDSv, rg, tilev, s0, s1, s2, s3, ob);
    tile_step<3, 1>(bk, s, q, t, h0, perLDSv, rg, tilev, s0, s1, s2, s3, ob);
    tile_step<4, 0>(bk, s, q, t, h0, perLDSv, rg, tilev, s0, s1, s2, s3, ob);
    tile_step<4, 1>(bk, s, q, t, h0, perLDSv, rg, tilev, s0, s1, s2, s3, ob);
    tile_step<5, 0>(bk, s, q, t, h0, perLDSv, rg, tilev, s0, s1, s2, s3, ob);
    tile_step<5, 1>(bk, s, q, t, h0, perLDSv, rg, tilev, s0, s1, s2, s3, ob);
    tile_step<6, 0>(bk, s, q, t, h0, perLDSv, rg, tilev, s0, s1, s2, s3, ob);
    tile_step<6, 1>(bk, s, q, t, h0, perLDSv, rg, tilev, s0, s1, s2, s3, ob);
    tile_step<7, 0>(bk, s, q, t, h0, perLDSv, rg, tilev, s0, s1, s2, s3, ob);
    tile_step<7, 1>(bk, s, q, t, h0, perLDSv, rg, tilev, s0, s1, s2, s3, ob);
}

extern "C" void kernel_launch(void* const* d_in, const int* in_sizes, int n_in,
                              void* d_out, int out_size, void* d_ws, size_t ws_size,
                              hipStream_t stream) {
    const float* x    = (const float*)d_in[0];
    const float* Wsel = (const float*)d_in[1];
    const float* bsel = (const float*)d_in[2];
    float* out = (float*)d_out;

    float*    partial = (float*)d_ws;                       // 256*4 floats
    unsigned* cnt     = (unsigned*)((char*)d_ws + 4096);

    hipMemsetAsync(cnt, 0, sizeof(unsigned), stream);
    fused_rot<<<256, 512, 0, stream>>>(x, Wsel, bsel, out, partial, cnt);
}